// Round 6
// baseline (594.278 us; speedup 1.0000x reference)
//
#include <hip/hip_runtime.h>

// ---------------------------------------------------------------------------
// 3-layer GCN. Factorized: tmp[n] = dinv[n]*(h[n]@W); agg[i]=dinv[i]*(tmp[i]+sum tmp[src])+b
// All fp32 (threshold ~1e-5 relative of max|out|~488; bf16 forbidden).
// GEMM v6: 2-wave blocks, thread-tile 8x8 (1 b128 per 16 wave-FMA: LDS-pipe
// demand 1.5x VALU, vs 2.25x in v2), KB=16 dbuf via global_load_lds,
// conflict-free A chunk-XOR + W stride-C/2 column quads. ~12 waves/CU.
// ---------------------------------------------------------------------------

// ---------------- CSR build ----------------

__global__ __launch_bounds__(256) void count_kernel(const int* __restrict__ dst,
                                                    int* __restrict__ cnt, int E) {
    int e = blockIdx.x * 256 + threadIdx.x;
    if (e < E) atomicAdd(&cnt[dst[e]], 1);
}

__global__ __launch_bounds__(256) void dinv_kernel(const int* __restrict__ cnt,
                                                   float* __restrict__ dinv, int M) {
    int i = blockIdx.x * 256 + threadIdx.x;
    if (i < M) dinv[i] = 1.0f / sqrtf((float)cnt[i] + 1.0f);  // +1: self-loop
}

__global__ __launch_bounds__(256) void scan1_kernel(const int* __restrict__ cnt,
                                                    int* __restrict__ loc,
                                                    int* __restrict__ bsum, int M) {
    __shared__ int sm[256];
    int t = threadIdx.x;
    int i = blockIdx.x * 256 + t;
    int v = (i < M) ? cnt[i] : 0;
    sm[t] = v;
    __syncthreads();
    for (int o = 1; o < 256; o <<= 1) {
        int add = (t >= o) ? sm[t - o] : 0;
        __syncthreads();
        sm[t] += add;
        __syncthreads();
    }
    if (i < M) loc[i] = sm[t] - v;
    if (t == 255) bsum[blockIdx.x] = sm[255];
}

__global__ __launch_bounds__(256) void scan2_kernel(int* __restrict__ bsum, int NB) {
    __shared__ int sm[256];
    int t = threadIdx.x;
    int v = (t < NB) ? bsum[t] : 0;
    sm[t] = v;
    __syncthreads();
    for (int o = 1; o < 256; o <<= 1) {
        int add = (t >= o) ? sm[t - o] : 0;
        __syncthreads();
        sm[t] += add;
        __syncthreads();
    }
    if (t < NB) bsum[t] = sm[t] - v;
}

__global__ __launch_bounds__(256) void place_kernel(const int* __restrict__ src,
                                                    const int* __restrict__ dst,
                                                    const int* __restrict__ loc,
                                                    const int* __restrict__ base,
                                                    int* __restrict__ fill,
                                                    int* __restrict__ srcs, int E) {
    int e = blockIdx.x * 256 + threadIdx.x;
    if (e >= E) return;
    int d = dst[e];
    int pos = loc[d] + base[d >> 8] + atomicAdd(&fill[d], 1);
    srcs[pos] = src[e];
}

// ---------------- GEMM v6 ----------------
// 128 threads = 2 waves. COLG = C/8 col-groups (tx), ROWG = 128/COLG row-groups
// (ty). Tile TM = 8*ROWG rows x C cols (C=128 -> 64x128 grid 782; C=64 ->
// 128x64 grid 391). Thread: 8 rows (r = i*ROWG+ty) x 8 cols (tx*4 + j*C/2).
// KB=16 double-buffered via global_load_lds; A chunk-XOR kq^(r&3) both sides.

__device__ __forceinline__ void gload_lds16(const float* g, float* l) {
    __builtin_amdgcn_global_load_lds((const __attribute__((address_space(1))) void*)g,
                                     (__attribute__((address_space(3))) void*)l,
                                     16, 0, 0);
}

template <int K, int C>
__global__ __launch_bounds__(128, 3) void gemm_v6(const float* __restrict__ A,
                                                  const float* __restrict__ W,
                                                  const float* __restrict__ dinv,
                                                  float* __restrict__ out, int M) {
    constexpr int KB = 16;
    constexpr int COLG = C / 8;          // 16 (C=128) / 8 (C=64)
    constexpr int ROWG = 128 / COLG;     // 8 / 16
    constexpr int TM = 8 * ROWG;         // 64 / 128
    constexpr int NCH = K / KB;
    constexpr int AFL = TM * KB;         // 1024 / 2048 floats
    constexpr int WFL = KB * C;          // 2048 / 1024 floats
    constexpr int AR = AFL / (4 * 128);  // A stage rounds: 2 / 4
    constexpr int WR = WFL / (4 * 128);  // W stage rounds: 4 / 2

    __shared__ __align__(16) float Ab[2][AFL];
    __shared__ __align__(16) float Wb[2][WFL];

    const int t = threadIdx.x;
    const int tx = t % COLG;
    const int ty = t / COLG;             // 0..ROWG-1
    const int row0 = blockIdx.x * TM;

    auto stage = [&](int ch, int buf) {
        const int k0 = ch * KB;
#pragma unroll
        for (int rnd = 0; rnd < AR; ++rnd) {
            int L = rnd * 128 + t;
            int r = L >> 2;
            int cp = L & 3;
            int gc = cp ^ (r & 3);           // inverse swizzle on global source
            int grow = row0 + r;
            if (grow >= M) grow = M - 1;     // clamped rows never stored
            gload_lds16(A + (size_t)grow * K + k0 + gc * 4, &Ab[buf][L * 4]);
        }
#pragma unroll
        for (int rnd = 0; rnd < WR; ++rnd) {
            int L = rnd * 128 + t;
            gload_lds16(W + (size_t)k0 * C + L * 4, &Wb[buf][L * 4]);
        }
    };

    float acc[8][8];
#pragma unroll
    for (int i = 0; i < 8; ++i)
#pragma unroll
        for (int j = 0; j < 8; ++j) acc[i][j] = 0.f;

    stage(0, 0);
    __syncthreads();

    for (int ch = 0; ch < NCH; ++ch) {
        if (ch + 1 < NCH) stage(ch + 1, (ch + 1) & 1);   // prefetch next chunk
        const float* Abuf = Ab[ch & 1];
        const float* Wbuf = Wb[ch & 1];
#pragma unroll
        for (int kq = 0; kq < KB / 4; ++kq) {
            float4 a[8];
#pragma unroll
            for (int i = 0; i < 8; ++i) {
                int r = i * ROWG + ty;
                a[i] = *(const float4*)&Abuf[r * KB + ((kq ^ (r & 3)) << 2)];
            }
#pragma unroll
            for (int kk = 0; kk < 4; ++kk) {
                const int k = kq * 4 + kk;
                float4 w0 = *(const float4*)&Wbuf[k * C + tx * 4];
                float4 w1 = *(const float4*)&Wbuf[k * C + C / 2 + tx * 4];
#pragma unroll
                for (int i = 0; i < 8; ++i) {
                    float av = (&a[i].x)[kk];
                    acc[i][0] += av * w0.x; acc[i][1] += av * w0.y;
                    acc[i][2] += av * w0.z; acc[i][3] += av * w0.w;
                    acc[i][4] += av * w1.x; acc[i][5] += av * w1.y;
                    acc[i][6] += av * w1.z; acc[i][7] += av * w1.w;
                }
            }
        }
        __syncthreads();   // prefetch issued ~whole-chunk ago: latency hidden
    }

#pragma unroll
    for (int i = 0; i < 8; ++i) {
        int r = row0 + i * ROWG + ty;
        if (r < M) {
            float dv = dinv[r];
            float4 v0 = make_float4(acc[i][0] * dv, acc[i][1] * dv,
                                    acc[i][2] * dv, acc[i][3] * dv);
            float4 v1 = make_float4(acc[i][4] * dv, acc[i][5] * dv,
                                    acc[i][6] * dv, acc[i][7] * dv);
            *(float4*)(out + (size_t)r * C + tx * 4) = v0;
            *(float4*)(out + (size_t)r * C + C / 2 + tx * 4) = v1;
        }
    }
}

// ---------------- Aggregation: out[i] = act(dinv[i]*(tmp[i] + sum tmp[src]) + b) ----------------
// Unroll x8 with index prefetch: 8 independent gathers in flight per thread.

template <int C, bool RELU>
__global__ __launch_bounds__(256) void agg_kernel(const float* __restrict__ tmp,
                                                  const int* __restrict__ srcs,
                                                  const int* __restrict__ cnt,
                                                  const int* __restrict__ loc,
                                                  const int* __restrict__ base,
                                                  const float* __restrict__ dinv,
                                                  const float* __restrict__ bias,
                                                  float* __restrict__ out, int M) {
    constexpr int TPN = C / 4;        // threads per node (float4 per thread)
    constexpr int NPB = 256 / TPN;    // nodes per block
    const int t = threadIdx.x;
    const int cq = t % TPN;
    const int node = blockIdx.x * NPB + t / TPN;
    if (node >= M) return;

    const float4* tmp4 = (const float4*)tmp;
    float4 acc = tmp4[(size_t)node * TPN + cq];   // self-loop term
    float4 acc2 = make_float4(0.f, 0.f, 0.f, 0.f);
    const int start = loc[node] + base[node >> 8];
    const int n = cnt[node];
    const int* sp = srcs + start;

    const int jn = n & ~7;
    int s[8];
    if (jn > 0) {
#pragma unroll
        for (int u = 0; u < 8; ++u) s[u] = sp[u];
    }
    for (int j = 0; j < jn; j += 8) {
        float4 v0 = tmp4[(size_t)s[0] * TPN + cq];
        float4 v1 = tmp4[(size_t)s[1] * TPN + cq];
        float4 v2 = tmp4[(size_t)s[2] * TPN + cq];
        float4 v3 = tmp4[(size_t)s[3] * TPN + cq];
        float4 v4 = tmp4[(size_t)s[4] * TPN + cq];
        float4 v5 = tmp4[(size_t)s[5] * TPN + cq];
        float4 v6 = tmp4[(size_t)s[6] * TPN + cq];
        float4 v7 = tmp4[(size_t)s[7] * TPN + cq];
        if (j + 8 < jn) {
#pragma unroll
            for (int u = 0; u < 8; ++u) s[u] = sp[j + 8 + u];
        }
        acc.x  += v0.x + v1.x;  acc.y  += v0.y + v1.y;
        acc.z  += v0.z + v1.z;  acc.w  += v0.w + v1.w;
        acc2.x += v2.x + v3.x;  acc2.y += v2.y + v3.y;
        acc2.z += v2.z + v3.z;  acc2.w += v2.w + v3.w;
        acc.x  += v4.x + v5.x;  acc.y  += v4.y + v5.y;
        acc.z  += v4.z + v5.z;  acc.w  += v4.w + v5.w;
        acc2.x += v6.x + v7.x;  acc2.y += v6.y + v7.y;
        acc2.z += v6.z + v7.z;  acc2.w += v6.w + v7.w;
    }
    for (int j = jn; j < n; ++j) {
        float4 v = tmp4[(size_t)sp[j] * TPN + cq];
        acc.x += v.x; acc.y += v.y; acc.z += v.z; acc.w += v.w;
    }
    acc.x += acc2.x; acc.y += acc2.y; acc.z += acc2.z; acc.w += acc2.w;

    float dv = dinv[node];
    float4 b = *(const float4*)(bias + cq * 4);
    float4 r;
    r.x = acc.x * dv + b.x;
    r.y = acc.y * dv + b.y;
    r.z = acc.z * dv + b.z;
    r.w = acc.w * dv + b.w;
    if (RELU) {
        r.x = fmaxf(r.x, 0.f); r.y = fmaxf(r.y, 0.f);
        r.z = fmaxf(r.z, 0.f); r.w = fmaxf(r.w, 0.f);
    }
    ((float4*)out)[(size_t)node * TPN + cq] = r;
}

// ---------------- launch ----------------

extern "C" void kernel_launch(void* const* d_in, const int* in_sizes, int n_in,
                              void* d_out, int out_size, void* d_ws, size_t ws_size,
                              hipStream_t stream) {
    const float* x  = (const float*)d_in[0];
    const int*   ei = (const int*)d_in[1];
    const float* W1 = (const float*)d_in[2];
    const float* b1 = (const float*)d_in[3];
    const float* W2 = (const float*)d_in[4];
    const float* b2 = (const float*)d_in[5];
    const float* W3 = (const float*)d_in[6];
    const float* b3 = (const float*)d_in[7];
    float* out = (float*)d_out;

    const int M = in_sizes[0] / 256;   // 50000 nodes
    const int E = in_sizes[1] / 2;     // 800000 edges
    const int NB = (M + 255) / 256;

    char* p = (char*)d_ws;
    auto alloc = [&](size_t bytes) {
        char* r = p;
        p += (bytes + 255) & ~(size_t)255;
        return r;
    };
    int*   cnt  = (int*)alloc((size_t)M * 4);
    int*   fill = (int*)alloc((size_t)M * 4);
    int*   loc  = (int*)alloc((size_t)M * 4);
    int*   base = (int*)alloc((size_t)NB * 4);
    float* dinv = (float*)alloc((size_t)M * 4);
    int*   srcs = (int*)alloc((size_t)E * 4);
    float* tmp  = (float*)alloc((size_t)M * 128 * 4);
    float* h    = (float*)alloc((size_t)M * 128 * 4);

    hipMemsetAsync(cnt, 0, (size_t)M * 4, stream);
    hipMemsetAsync(fill, 0, (size_t)M * 4, stream);

    const int* esrc = ei;
    const int* edst = ei + E;

    count_kernel<<<(E + 255) / 256, 256, 0, stream>>>(edst, cnt, E);
    dinv_kernel<<<(M + 255) / 256, 256, 0, stream>>>(cnt, dinv, M);
    scan1_kernel<<<NB, 256, 0, stream>>>(cnt, loc, base, M);
    scan2_kernel<<<1, 256, 0, stream>>>(base, NB);
    place_kernel<<<(E + 255) / 256, 256, 0, stream>>>(esrc, edst, loc, base, fill, srcs, E);

    // layer 1: x[50000,256] @ W1[256,128] -> relu agg -> h   (tile 64x128)
    gemm_v6<256, 128><<<(M + 63) / 64, 128, 0, stream>>>(x, W1, dinv, tmp, M);
    agg_kernel<128, true><<<(M + 7) / 8, 256, 0, stream>>>(tmp, srcs, cnt, loc, base, dinv, b1, h, M);

    // layer 2: h @ W2[128,128] -> relu agg -> h              (tile 64x128)
    gemm_v6<128, 128><<<(M + 63) / 64, 128, 0, stream>>>(h, W2, dinv, tmp, M);
    agg_kernel<128, true><<<(M + 7) / 8, 256, 0, stream>>>(tmp, srcs, cnt, loc, base, dinv, b2, h, M);

    // layer 3: h @ W3[128,64] -> agg -> out                  (tile 128x64)
    gemm_v6<128, 64><<<(M + 127) / 128, 128, 0, stream>>>(h, W3, dinv, tmp, M);
    agg_kernel<64, false><<<(M + 15) / 16, 256, 0, stream>>>(tmp, srcs, cnt, loc, base, dinv, b3, out, M);
}

// Round 7
// 377.908 us; speedup vs baseline: 1.5725x; 1.5725x over previous
//
#include <hip/hip_runtime.h>

// ---------------------------------------------------------------------------
// 3-layer GCN. Factorized: tmp[n] = dinv[n]*(h[n]@W); agg[i]=dinv[i]*(tmp[i]+sum tmp[src])+b
// All fp32 (threshold ~1e-5 relative of max|out|~488; bf16 forbidden).
// GEMM v7 = v6 without the launch_bounds min-occupancy arg (v6's `,3` capped
// VGPRs at ~85 -> acc[8][8] spilled to scratch: WRITE_SIZE 406MB, 227us).
// 2-wave blocks, thread-tile 8x8 (LDS-pipe demand 0.37x VALU), KB=16 dbuf via
// global_load_lds, conflict-free A chunk-XOR + W stride-C/2 column quads.
// ---------------------------------------------------------------------------

// ---------------- CSR build ----------------

__global__ __launch_bounds__(256) void count_kernel(const int* __restrict__ dst,
                                                    int* __restrict__ cnt, int E) {
    int e = blockIdx.x * 256 + threadIdx.x;
    if (e < E) atomicAdd(&cnt[dst[e]], 1);
}

__global__ __launch_bounds__(256) void dinv_kernel(const int* __restrict__ cnt,
                                                   float* __restrict__ dinv, int M) {
    int i = blockIdx.x * 256 + threadIdx.x;
    if (i < M) dinv[i] = 1.0f / sqrtf((float)cnt[i] + 1.0f);  // +1: self-loop
}

__global__ __launch_bounds__(256) void scan1_kernel(const int* __restrict__ cnt,
                                                    int* __restrict__ loc,
                                                    int* __restrict__ bsum, int M) {
    __shared__ int sm[256];
    int t = threadIdx.x;
    int i = blockIdx.x * 256 + t;
    int v = (i < M) ? cnt[i] : 0;
    sm[t] = v;
    __syncthreads();
    for (int o = 1; o < 256; o <<= 1) {
        int add = (t >= o) ? sm[t - o] : 0;
        __syncthreads();
        sm[t] += add;
        __syncthreads();
    }
    if (i < M) loc[i] = sm[t] - v;
    if (t == 255) bsum[blockIdx.x] = sm[255];
}

__global__ __launch_bounds__(256) void scan2_kernel(int* __restrict__ bsum, int NB) {
    __shared__ int sm[256];
    int t = threadIdx.x;
    int v = (t < NB) ? bsum[t] : 0;
    sm[t] = v;
    __syncthreads();
    for (int o = 1; o < 256; o <<= 1) {
        int add = (t >= o) ? sm[t - o] : 0;
        __syncthreads();
        sm[t] += add;
        __syncthreads();
    }
    if (t < NB) bsum[t] = sm[t] - v;
}

__global__ __launch_bounds__(256) void place_kernel(const int* __restrict__ src,
                                                    const int* __restrict__ dst,
                                                    const int* __restrict__ loc,
                                                    const int* __restrict__ base,
                                                    int* __restrict__ fill,
                                                    int* __restrict__ srcs, int E) {
    int e = blockIdx.x * 256 + threadIdx.x;
    if (e >= E) return;
    int d = dst[e];
    int pos = loc[d] + base[d >> 8] + atomicAdd(&fill[d], 1);
    srcs[pos] = src[e];
}

// ---------------- GEMM v7 ----------------
// 128 threads = 2 waves. COLG = C/8 col-groups (tx), ROWG = 128/COLG row-groups
// (ty). Tile TM = 8*ROWG rows x C cols (C=128 -> 64x128 grid 782; C=64 ->
// 128x64 grid 391). Thread: 8 rows (r = i*ROWG+ty) x 8 cols (tx*4 + j*C/2).
// KB=16 double-buffered via global_load_lds; A chunk-XOR kq^(r&3) both sides.

__device__ __forceinline__ void gload_lds16(const float* g, float* l) {
    __builtin_amdgcn_global_load_lds((const __attribute__((address_space(1))) void*)g,
                                     (__attribute__((address_space(3))) void*)l,
                                     16, 0, 0);
}

template <int K, int C>
__global__ __launch_bounds__(128) void gemm_v7(const float* __restrict__ A,
                                               const float* __restrict__ W,
                                               const float* __restrict__ dinv,
                                               float* __restrict__ out, int M) {
    constexpr int KB = 16;
    constexpr int COLG = C / 8;          // 16 (C=128) / 8 (C=64)
    constexpr int ROWG = 128 / COLG;     // 8 / 16
    constexpr int TM = 8 * ROWG;         // 64 / 128
    constexpr int NCH = K / KB;
    constexpr int AFL = TM * KB;         // 1024 / 2048 floats
    constexpr int WFL = KB * C;          // 2048 / 1024 floats
    constexpr int AR = AFL / (4 * 128);  // A stage rounds: 2 / 4
    constexpr int WR = WFL / (4 * 128);  // W stage rounds: 4 / 2

    __shared__ __align__(16) float Ab[2][AFL];
    __shared__ __align__(16) float Wb[2][WFL];

    const int t = threadIdx.x;
    const int tx = t % COLG;
    const int ty = t / COLG;             // 0..ROWG-1
    const int row0 = blockIdx.x * TM;

    auto stage = [&](int ch, int buf) {
        const int k0 = ch * KB;
#pragma unroll
        for (int rnd = 0; rnd < AR; ++rnd) {
            int L = rnd * 128 + t;
            int r = L >> 2;
            int cp = L & 3;
            int gc = cp ^ (r & 3);           // inverse swizzle on global source
            int grow = row0 + r;
            if (grow >= M) grow = M - 1;     // clamped rows never stored
            gload_lds16(A + (size_t)grow * K + k0 + gc * 4, &Ab[buf][L * 4]);
        }
#pragma unroll
        for (int rnd = 0; rnd < WR; ++rnd) {
            int L = rnd * 128 + t;
            gload_lds16(W + (size_t)k0 * C + L * 4, &Wb[buf][L * 4]);
        }
    };

    float acc[8][8];
#pragma unroll
    for (int i = 0; i < 8; ++i)
#pragma unroll
        for (int j = 0; j < 8; ++j) acc[i][j] = 0.f;

    stage(0, 0);
    __syncthreads();

    for (int ch = 0; ch < NCH; ++ch) {
        if (ch + 1 < NCH) stage(ch + 1, (ch + 1) & 1);   // prefetch next chunk
        const float* Abuf = Ab[ch & 1];
        const float* Wbuf = Wb[ch & 1];
#pragma unroll
        for (int kq = 0; kq < KB / 4; ++kq) {
            float4 a[8];
#pragma unroll
            for (int i = 0; i < 8; ++i) {
                int r = i * ROWG + ty;
                a[i] = *(const float4*)&Abuf[r * KB + ((kq ^ (r & 3)) << 2)];
            }
#pragma unroll
            for (int kk = 0; kk < 4; ++kk) {
                const int k = kq * 4 + kk;
                float4 w0 = *(const float4*)&Wbuf[k * C + tx * 4];
                float4 w1 = *(const float4*)&Wbuf[k * C + C / 2 + tx * 4];
#pragma unroll
                for (int i = 0; i < 8; ++i) {
                    float av = (&a[i].x)[kk];
                    acc[i][0] += av * w0.x; acc[i][1] += av * w0.y;
                    acc[i][2] += av * w0.z; acc[i][3] += av * w0.w;
                    acc[i][4] += av * w1.x; acc[i][5] += av * w1.y;
                    acc[i][6] += av * w1.z; acc[i][7] += av * w1.w;
                }
            }
        }
        __syncthreads();   // prefetch issued ~whole-chunk ago: latency hidden
    }

#pragma unroll
    for (int i = 0; i < 8; ++i) {
        int r = row0 + i * ROWG + ty;
        if (r < M) {
            float dv = dinv[r];
            float4 v0 = make_float4(acc[i][0] * dv, acc[i][1] * dv,
                                    acc[i][2] * dv, acc[i][3] * dv);
            float4 v1 = make_float4(acc[i][4] * dv, acc[i][5] * dv,
                                    acc[i][6] * dv, acc[i][7] * dv);
            *(float4*)(out + (size_t)r * C + tx * 4) = v0;
            *(float4*)(out + (size_t)r * C + C / 2 + tx * 4) = v1;
        }
    }
}

// ---------------- Aggregation: out[i] = act(dinv[i]*(tmp[i] + sum tmp[src]) + b) ----------------
// Unroll x8 with index prefetch: 8 independent gathers in flight per thread.

template <int C, bool RELU>
__global__ __launch_bounds__(256) void agg_kernel(const float* __restrict__ tmp,
                                                  const int* __restrict__ srcs,
                                                  const int* __restrict__ cnt,
                                                  const int* __restrict__ loc,
                                                  const int* __restrict__ base,
                                                  const float* __restrict__ dinv,
                                                  const float* __restrict__ bias,
                                                  float* __restrict__ out, int M) {
    constexpr int TPN = C / 4;        // threads per node (float4 per thread)
    constexpr int NPB = 256 / TPN;    // nodes per block
    const int t = threadIdx.x;
    const int cq = t % TPN;
    const int node = blockIdx.x * NPB + t / TPN;
    if (node >= M) return;

    const float4* tmp4 = (const float4*)tmp;
    float4 acc = tmp4[(size_t)node * TPN + cq];   // self-loop term
    float4 acc2 = make_float4(0.f, 0.f, 0.f, 0.f);
    const int start = loc[node] + base[node >> 8];
    const int n = cnt[node];
    const int* sp = srcs + start;

    const int jn = n & ~7;
    int s[8];
    if (jn > 0) {
#pragma unroll
        for (int u = 0; u < 8; ++u) s[u] = sp[u];
    }
    for (int j = 0; j < jn; j += 8) {
        float4 v0 = tmp4[(size_t)s[0] * TPN + cq];
        float4 v1 = tmp4[(size_t)s[1] * TPN + cq];
        float4 v2 = tmp4[(size_t)s[2] * TPN + cq];
        float4 v3 = tmp4[(size_t)s[3] * TPN + cq];
        float4 v4 = tmp4[(size_t)s[4] * TPN + cq];
        float4 v5 = tmp4[(size_t)s[5] * TPN + cq];
        float4 v6 = tmp4[(size_t)s[6] * TPN + cq];
        float4 v7 = tmp4[(size_t)s[7] * TPN + cq];
        if (j + 8 < jn) {
#pragma unroll
            for (int u = 0; u < 8; ++u) s[u] = sp[j + 8 + u];
        }
        acc.x  += v0.x + v1.x;  acc.y  += v0.y + v1.y;
        acc.z  += v0.z + v1.z;  acc.w  += v0.w + v1.w;
        acc2.x += v2.x + v3.x;  acc2.y += v2.y + v3.y;
        acc2.z += v2.z + v3.z;  acc2.w += v2.w + v3.w;
        acc.x  += v4.x + v5.x;  acc.y  += v4.y + v5.y;
        acc.z  += v4.z + v5.z;  acc.w  += v4.w + v5.w;
        acc2.x += v6.x + v7.x;  acc2.y += v6.y + v7.y;
        acc2.z += v6.z + v7.z;  acc2.w += v6.w + v7.w;
    }
    for (int j = jn; j < n; ++j) {
        float4 v = tmp4[(size_t)sp[j] * TPN + cq];
        acc.x += v.x; acc.y += v.y; acc.z += v.z; acc.w += v.w;
    }
    acc.x += acc2.x; acc.y += acc2.y; acc.z += acc2.z; acc.w += acc2.w;

    float dv = dinv[node];
    float4 b = *(const float4*)(bias + cq * 4);
    float4 r;
    r.x = acc.x * dv + b.x;
    r.y = acc.y * dv + b.y;
    r.z = acc.z * dv + b.z;
    r.w = acc.w * dv + b.w;
    if (RELU) {
        r.x = fmaxf(r.x, 0.f); r.y = fmaxf(r.y, 0.f);
        r.z = fmaxf(r.z, 0.f); r.w = fmaxf(r.w, 0.f);
    }
    ((float4*)out)[(size_t)node * TPN + cq] = r;
}

// ---------------- launch ----------------

extern "C" void kernel_launch(void* const* d_in, const int* in_sizes, int n_in,
                              void* d_out, int out_size, void* d_ws, size_t ws_size,
                              hipStream_t stream) {
    const float* x  = (const float*)d_in[0];
    const int*   ei = (const int*)d_in[1];
    const float* W1 = (const float*)d_in[2];
    const float* b1 = (const float*)d_in[3];
    const float* W2 = (const float*)d_in[4];
    const float* b2 = (const float*)d_in[5];
    const float* W3 = (const float*)d_in[6];
    const float* b3 = (const float*)d_in[7];
    float* out = (float*)d_out;

    const int M = in_sizes[0] / 256;   // 50000 nodes
    const int E = in_sizes[1] / 2;     // 800000 edges
    const int NB = (M + 255) / 256;

    char* p = (char*)d_ws;
    auto alloc = [&](size_t bytes) {
        char* r = p;
        p += (bytes + 255) & ~(size_t)255;
        return r;
    };
    int*   cnt  = (int*)alloc((size_t)M * 4);
    int*   fill = (int*)alloc((size_t)M * 4);
    int*   loc  = (int*)alloc((size_t)M * 4);
    int*   base = (int*)alloc((size_t)NB * 4);
    float* dinv = (float*)alloc((size_t)M * 4);
    int*   srcs = (int*)alloc((size_t)E * 4);
    float* tmp  = (float*)alloc((size_t)M * 128 * 4);
    float* h    = (float*)alloc((size_t)M * 128 * 4);

    hipMemsetAsync(cnt, 0, (size_t)M * 4, stream);
    hipMemsetAsync(fill, 0, (size_t)M * 4, stream);

    const int* esrc = ei;
    const int* edst = ei + E;

    count_kernel<<<(E + 255) / 256, 256, 0, stream>>>(edst, cnt, E);
    dinv_kernel<<<(M + 255) / 256, 256, 0, stream>>>(cnt, dinv, M);
    scan1_kernel<<<NB, 256, 0, stream>>>(cnt, loc, base, M);
    scan2_kernel<<<1, 256, 0, stream>>>(base, NB);
    place_kernel<<<(E + 255) / 256, 256, 0, stream>>>(esrc, edst, loc, base, fill, srcs, E);

    // layer 1: x[50000,256] @ W1[256,128] -> relu agg -> h   (tile 64x128)
    gemm_v7<256, 128><<<(M + 63) / 64, 128, 0, stream>>>(x, W1, dinv, tmp, M);
    agg_kernel<128, true><<<(M + 7) / 8, 256, 0, stream>>>(tmp, srcs, cnt, loc, base, dinv, b1, h, M);

    // layer 2: h @ W2[128,128] -> relu agg -> h              (tile 64x128)
    gemm_v7<128, 128><<<(M + 63) / 64, 128, 0, stream>>>(h, W2, dinv, tmp, M);
    agg_kernel<128, true><<<(M + 7) / 8, 256, 0, stream>>>(tmp, srcs, cnt, loc, base, dinv, b2, h, M);

    // layer 3: h @ W3[128,64] -> agg -> out                  (tile 128x64)
    gemm_v7<128, 64><<<(M + 127) / 128, 128, 0, stream>>>(h, W3, dinv, tmp, M);
    agg_kernel<64, false><<<(M + 15) / 16, 256, 0, stream>>>(tmp, srcs, cnt, loc, base, dinv, b3, out, M);
}